// Round 5
// baseline (24.170 us; speedup 1.0000x reference)
//
#include <hip/hip_runtime.h>

// Crop 128x128 patch per image at starts[b], bilinear x4 upsample to 512x512.
// Each thread computes a 4x4 output block (one 16B store per row) from a
// 3x3 input neighborhood. Half-pixel-center bilinear, clamped indices
// (== jax.image.resize renormalized edge weights for this 4x config).
//
// block=256 (R3 best). Plain cached stores: output is 100.7 MB < 256 MB
// Infinity Cache, so let the MALL absorb writes instead of nt-bypassing
// to HBM (nt regressed the write path to HBM drain rate).

#define PP   128
#define HH   512
#define WW   512
#define CC   3

typedef float f32x4 __attribute__((ext_vector_type(4)));

__global__ __launch_bounds__(256) void crop_resize4x_blk_kernel(
    const float* __restrict__ in,      // [B,C,H,W]
    const int*   __restrict__ starts,  // [B,2]
    float*       __restrict__ out)     // [B,C,H,W]
{
    const int t  = blockIdx.x * blockDim.x + threadIdx.x;
    // decompose: qx (128), qy (128), bc (B*C)
    const int qx = t & 127;
    const int qy = (t >> 7) & 127;
    const int bc = t >> 14;
    const int b  = bc / 3;             // compiler magic-div, once per thread

    const int s0 = starts[2 * b];
    const int s1 = starts[2 * b + 1];
    const float* patch = in + ((size_t)bc * HH + s0) * WW + s1;

    // 3 input rows (clamped) and 3 input cols (clamped)
    const int ya = max(qy - 1, 0);
    const int yc = min(qy + 1, PP - 1);
    const int xa = max(qx - 1, 0);
    const int xc = min(qx + 1, PP - 1);

    const float* rA = patch + (size_t)ya * WW;
    const float* rB = patch + (size_t)qy * WW;
    const float* rC = patch + (size_t)yc * WW;

    // 9 input values
    const float aA = rA[xa], aB = rA[qx], aC = rA[xc];
    const float bA = rB[xa], bB = rB[qx], bC = rB[xc];
    const float cA = rC[xa], cB = rC[qx], cC = rC[xc];

    // vertical blends for the 4 output rows, per column
    // ry=0: .375*up + .625*mid ; ry=1: .125*up + .875*mid
    // ry=2: .875*mid + .125*dn ; ry=3: .625*mid + .375*dn
    float vA[4], vB[4], vC[4];
    vA[0] = 0.375f * aA + 0.625f * bA;
    vB[0] = 0.375f * aB + 0.625f * bB;
    vC[0] = 0.375f * aC + 0.625f * bC;
    vA[1] = 0.125f * aA + 0.875f * bA;
    vB[1] = 0.125f * aB + 0.875f * bB;
    vC[1] = 0.125f * aC + 0.875f * bC;
    vA[2] = 0.875f * bA + 0.125f * cA;
    vB[2] = 0.875f * bB + 0.125f * cB;
    vC[2] = 0.875f * bC + 0.125f * cC;
    vA[3] = 0.625f * bA + 0.375f * cA;
    vB[3] = 0.625f * bB + 0.375f * cB;
    vC[3] = 0.625f * bC + 0.375f * cC;

    float* orow = out + ((size_t)bc * HH + ((size_t)qy << 2)) * WW + ((size_t)qx << 2);

    #pragma unroll
    for (int ry = 0; ry < 4; ++ry) {
        f32x4 o;
        o.x = 0.375f * vA[ry] + 0.625f * vB[ry];
        o.y = 0.125f * vA[ry] + 0.875f * vB[ry];
        o.z = 0.875f * vB[ry] + 0.125f * vC[ry];
        o.w = 0.625f * vB[ry] + 0.375f * vC[ry];
        *reinterpret_cast<f32x4*>(orow + (size_t)ry * WW) = o;
    }
}

extern "C" void kernel_launch(void* const* d_in, const int* in_sizes, int n_in,
                              void* d_out, int out_size, void* d_ws, size_t ws_size,
                              hipStream_t stream) {
    const float* in     = (const float*)d_in[0];
    const int*   starts = (const int*)d_in[1];
    float*       out    = (float*)d_out;

    const int B = in_sizes[1] / 2;                       // starts is [B,2]
    const int total_threads = B * CC * PP * PP;          // one 4x4 block each
    const int block = 256;
    const int grid = (total_threads + block - 1) / block;

    crop_resize4x_blk_kernel<<<grid, block, 0, stream>>>(in, starts, out);
}

// Round 6
// 22.278 us; speedup vs baseline: 1.0850x; 1.0850x over previous
//
#include <hip/hip_runtime.h>

// Crop 128x128 patch per image at starts[b], bilinear x4 upsample to 512x512.
// Each thread computes a 4-wide x 16-tall output tile (16 nontemporal 16B
// stores) from a 6-row x 3-col input neighborhood (18 scalar-per-lane loads).
// Half-pixel-center bilinear, clamped indices (== jax.image.resize
// renormalized edge weights for this 4x config).
//
// bc/b derived from blockIdx only -> starts loads + patch base are wave-
// uniform scalar ops. nt stores proven +12% vs cached (R5). Grid 1536x256.

#define PP   128
#define HH   512
#define WW   512
#define CC   3

typedef float f32x4 __attribute__((ext_vector_type(4)));

__global__ __launch_bounds__(256) void crop_resize4x_tall_kernel(
    const float* __restrict__ in,      // [B,C,H,W]
    const int*   __restrict__ starts,  // [B,2]
    float*       __restrict__ out)     // [B,C,H,W]
{
    // 16 blocks per (b,c) plane: blockIdx = bc*16 + sub
    const int bc  = blockIdx.x >> 4;           // uniform -> SGPR
    const int b   = bc / 3;                    // uniform -> SGPR
    const int t   = (blockIdx.x << 8) | threadIdx.x;
    const int qx  = t & 127;                   // quad column 0..127
    const int qys = (t >> 7) & 31;             // 16-row supergroup 0..31

    const int s0 = starts[2 * b];              // scalar loads (uniform addr)
    const int s1 = starts[2 * b + 1];
    const float* patch = in + ((size_t)bc * HH + s0) * WW + s1;

    const int xa = max(qx - 1, 0);
    const int xb = qx;
    const int xc = min(qx + 1, PP - 1);
    const int qy0 = qys << 2;                  // base quad-row (0,4,...,124)

    // 6 input rows (clamped) x 3 cols
    float r[6][3];
    #pragma unroll
    for (int j = 0; j < 6; ++j) {
        int ry = qy0 - 1 + j;
        ry = min(max(ry, 0), PP - 1);
        const float* row = patch + (size_t)ry * WW;
        r[j][0] = row[xa];
        r[j][1] = row[xb];
        r[j][2] = row[xc];
    }

    float* obase = out + ((size_t)bc * HH + ((size_t)qys << 4)) * WW
                       + ((size_t)qx << 2);

    // output quad-row qy0+g: up=r[g], mid=r[g+1], dn=r[g+2]
    #pragma unroll
    for (int g = 0; g < 4; ++g) {
        const float aA = r[g][0],     aB = r[g][1],     aC = r[g][2];
        const float bA = r[g + 1][0], bB = r[g + 1][1], bC = r[g + 1][2];
        const float cA = r[g + 2][0], cB = r[g + 2][1], cC = r[g + 2][2];

        float vA[4], vB[4], vC[4];
        vA[0] = 0.375f * aA + 0.625f * bA;
        vB[0] = 0.375f * aB + 0.625f * bB;
        vC[0] = 0.375f * aC + 0.625f * bC;
        vA[1] = 0.125f * aA + 0.875f * bA;
        vB[1] = 0.125f * aB + 0.875f * bB;
        vC[1] = 0.125f * aC + 0.875f * bC;
        vA[2] = 0.875f * bA + 0.125f * cA;
        vB[2] = 0.875f * bB + 0.125f * cB;
        vC[2] = 0.875f * bC + 0.125f * cC;
        vA[3] = 0.625f * bA + 0.375f * cA;
        vB[3] = 0.625f * bB + 0.375f * cB;
        vC[3] = 0.625f * bC + 0.375f * cC;

        #pragma unroll
        for (int ry = 0; ry < 4; ++ry) {
            f32x4 o;
            o.x = 0.375f * vA[ry] + 0.625f * vB[ry];
            o.y = 0.125f * vA[ry] + 0.875f * vB[ry];
            o.z = 0.875f * vB[ry] + 0.125f * vC[ry];
            o.w = 0.625f * vB[ry] + 0.375f * vC[ry];
            __builtin_nontemporal_store(
                o, reinterpret_cast<f32x4*>(obase + (size_t)(4 * g + ry) * WW));
        }
    }
}

extern "C" void kernel_launch(void* const* d_in, const int* in_sizes, int n_in,
                              void* d_out, int out_size, void* d_ws, size_t ws_size,
                              hipStream_t stream) {
    const float* in     = (const float*)d_in[0];
    const int*   starts = (const int*)d_in[1];
    float*       out    = (float*)d_out;

    const int B = in_sizes[1] / 2;             // starts is [B,2]
    const int grid = B * CC * 16;              // 16 blocks per (b,c) plane
    crop_resize4x_tall_kernel<<<grid, 256, 0, stream>>>(in, starts, out);
}